// Round 2
// baseline (1040.891 us; speedup 1.0000x reference)
//
#include <hip/hip_runtime.h>

#define CH 128
#define TM 128
#define BN_EPS 1e-4f

typedef unsigned short u16;
typedef u16 u16x8 __attribute__((ext_vector_type(8)));
typedef short bf16x8 __attribute__((ext_vector_type(8)));
typedef float f32x4 __attribute__((ext_vector_type(4)));

__device__ __forceinline__ float bf2f(u16 u) {
  union { unsigned int i; float f; } v; v.i = ((unsigned int)u) << 16; return v.f;
}
__device__ __forceinline__ u16 f2bf(float f) {
  union { float f; unsigned int i; } v; v.f = f;
  unsigned int r = v.i + 0x7fffu + ((v.i >> 16) & 1u);
  return (u16)(r >> 16);
}
__device__ __forceinline__ void lds_cp16(const void* g, void* l) {
  __builtin_amdgcn_global_load_lds((const __attribute__((address_space(1))) void*)g,
                                   (__attribute__((address_space(3))) void*)l, 16, 0, 0);
}

// ---------------------------------------------------------------------------
// prep_x: f32 [N,128] -> bf16 [N+1,128], row N = zeros (sentinel row)
// ---------------------------------------------------------------------------
__global__ __launch_bounds__(256) void prep_x(const float* __restrict__ x,
                                              u16* __restrict__ xb, int Nr) {
  int g = blockIdx.x * 256 + threadIdx.x;
  int total = (Nr + 1) * 16;           // 16 chunks of 8 per row
  int stride = gridDim.x * 256;
  for (int idx = g; idx < total; idx += stride) {
    u16x8 o;
    if (idx < Nr * 16) {
      const float* s = x + (size_t)idx * 8;
      f32x4 a = *(const f32x4*)s;
      f32x4 b = *(const f32x4*)(s + 4);
      #pragma unroll
      for (int j = 0; j < 4; ++j) { o[j] = f2bf(a[j]); o[4 + j] = f2bf(b[j]); }
    } else {
      #pragma unroll
      for (int j = 0; j < 8; ++j) o[j] = 0;
    }
    *(u16x8*)(xb + (size_t)idx * 8) = o;
  }
}

// ---------------------------------------------------------------------------
// prep_w: W [9][Cin][Cout] f32 -> Wt [9][Cout][Cin] bf16, PRE-SWIZZLED so a
// linear global_load_lds copy lands in the XOR-swizzled LDS layout.
// stored ushort index within a k-tile: co*128 + (((ci>>3)^(co&7))<<3) + (ci&7)
// ---------------------------------------------------------------------------
__global__ void prep_w(const float* __restrict__ W1, const float* __restrict__ W2,
                       u16* __restrict__ Wt1, u16* __restrict__ Wt2) {
  int b = blockIdx.x;                 // 18 blocks: [which][k]
  const float* src = (b < 9) ? W1 : W2;
  u16* dst = (b < 9) ? Wt1 : Wt2;
  int k = (b < 9) ? b : b - 9;
  src += (size_t)k * CH * CH;
  dst += (size_t)k * CH * CH;
  for (int t = threadIdx.x; t < CH * CH; t += blockDim.x) {
    int co = t & 127, ci = t >> 7;    // coalesced read over co
    float v = src[(size_t)ci * CH + co];
    int sw = co * CH + ((((ci >> 3) ^ (co & 7)) << 3) | (ci & 7));
    dst[sw] = f2bf(v);
  }
}

// ---------------------------------------------------------------------------
// conv_k: out[m][co] = sum_k sum_ci in[nbr[m][k]][ci] * W[k][ci][co]
// 128x128 tile, 4 waves (2x2 of 64x64), K staged per offset (9 iters).
// Also accumulates per-channel sum / sumsq of the fp32 outputs (BN stats).
// ---------------------------------------------------------------------------
__global__ __launch_bounds__(256, 2)
void conv_k(const u16* __restrict__ in,   // [N+1][128] bf16 (row N = zeros)
            const u16* __restrict__ Wt,   // [9][128][128] bf16 pre-swizzled
            const int* __restrict__ nbr,  // [N][9]
            u16* __restrict__ outh,       // [N][128] bf16
            float* __restrict__ gSum, float* __restrict__ gSq, int Nr) {
  __shared__ __align__(16) u16 Abuf[TM * CH];
  __shared__ __align__(16) u16 Bbuf[CH * CH];
  __shared__ int nbrs[TM * 9];
  __shared__ float smSum[CH], smSq[CH];

  const int tid = threadIdx.x;
  const int lane = tid & 63;
  const int w = tid >> 6;
  const int row0 = blockIdx.x * TM;
  const int l15 = lane & 15, lq = lane >> 4;
  const int wr = w >> 1, wc = w & 1;

  if (tid < CH) { smSum[tid] = 0.f; smSq[tid] = 0.f; }
  for (int i = tid; i < TM * 9; i += 256) {
    int r = i / 9;
    nbrs[i] = (row0 + r < Nr) ? nbr[(size_t)row0 * 9 + i] : Nr;
  }
  __syncthreads();

  f32x4 acc[4][4];
  const f32x4 zero = {0.f, 0.f, 0.f, 0.f};
  #pragma unroll
  for (int i = 0; i < 4; ++i)
    #pragma unroll
    for (int j = 0; j < 4; ++j) acc[i][j] = zero;

  for (int k = 0; k < 9; ++k) {
    // --- stage A: this wave stages rows w*32 .. w*32+31 (gather) ---
    const int rb = w * 32;
    #pragma unroll
    for (int it = 0; it < 8; ++it) {
      int r = rb + it * 4 + lq;                    // 4 rows per instruction
      int g = nbrs[r * 9 + k];                     // sentinel Nr -> zero row
      int srcChunk = l15 ^ (r & 7);                // pre-swizzled source chunk
      const u16* src = in + (size_t)g * CH + (srcChunk << 3);
      lds_cp16(src, &Abuf[(rb + it * 4) * CH]);
    }
    // --- stage B: wave's quarter of Wt[k] (already swizzled) ---
    const u16* wsrc = Wt + (size_t)k * CH * CH + w * 4096;
    #pragma unroll
    for (int it = 0; it < 8; ++it) {
      lds_cp16(wsrc + it * 512 + lane * 8, &Bbuf[w * 4096 + it * 512]);
    }
    __syncthreads();

    #pragma unroll
    for (int kc = 0; kc < 4; ++kc) {
      bf16x8 fa[4], fb[4];
      #pragma unroll
      for (int i = 0; i < 4; ++i) {
        int row = wr * 64 + i * 16 + l15;
        int chunk = (kc * 4 + lq) ^ (row & 7);
        fa[i] = *(const bf16x8*)&Abuf[row * CH + chunk * 8];
      }
      #pragma unroll
      for (int j = 0; j < 4; ++j) {
        int co = wc * 64 + j * 16 + l15;
        int chunk = (kc * 4 + lq) ^ (co & 7);
        fb[j] = *(const bf16x8*)&Bbuf[co * CH + chunk * 8];
      }
      #pragma unroll
      for (int i = 0; i < 4; ++i)
        #pragma unroll
        for (int j = 0; j < 4; ++j)
          acc[i][j] = __builtin_amdgcn_mfma_f32_16x16x32_bf16(fa[i], fb[j], acc[i][j], 0, 0, 0);
    }
    __syncthreads();
  }

  // --- BN stats from fp32 accumulators ---
  #pragma unroll
  for (int j = 0; j < 4; ++j) {
    float s = 0.f, q = 0.f;
    #pragma unroll
    for (int i = 0; i < 4; ++i)
      #pragma unroll
      for (int t = 0; t < 4; ++t) { float v = acc[i][j][t]; s += v; q += v * v; }
    s += __shfl_xor(s, 16); s += __shfl_xor(s, 32);
    q += __shfl_xor(q, 16); q += __shfl_xor(q, 32);
    if (lane < 16) {
      int col = wc * 64 + j * 16 + l15;
      atomicAdd(&smSum[col], s);
      atomicAdd(&smSq[col], q);
    }
  }

  // --- stage C into Abuf (bf16, swizzled) for coalesced global write ---
  #pragma unroll
  for (int i = 0; i < 4; ++i)
    #pragma unroll
    for (int j = 0; j < 4; ++j) {
      int col = wc * 64 + j * 16 + l15;
      #pragma unroll
      for (int t = 0; t < 4; ++t) {
        int row = wr * 64 + i * 16 + lq * 4 + t;
        int chunk = (col >> 3) ^ (row & 7);
        Abuf[row * CH + chunk * 8 + (col & 7)] = f2bf(acc[i][j][t]);
      }
    }
  __syncthreads();

  if (tid < CH) {
    atomicAdd(&gSum[tid], smSum[tid]);
    atomicAdd(&gSq[tid], smSq[tid]);
  }
  {
    int r = tid >> 1, half = tid & 1;
    if (row0 + r < Nr) {
      #pragma unroll
      for (int i = 0; i < 8; ++i) {
        int c = half * 8 + i;
        int chunk = c ^ (r & 7);
        u16x8 v = *(const u16x8*)&Abuf[r * CH + chunk * 8];
        *(u16x8*)(outh + (size_t)(row0 + r) * CH + c * 8) = v;
      }
    }
  }
}

// ---------------------------------------------------------------------------
// finalize_stats: sums -> per-channel scale/shift
// ---------------------------------------------------------------------------
__global__ void finalize_stats(const float* __restrict__ sum, const float* __restrict__ sq,
                               const float* __restrict__ gamma, const float* __restrict__ beta,
                               float* __restrict__ scale, float* __restrict__ shift, int Nr) {
  int c = threadIdx.x;
  if (c < CH) {
    float inv = 1.f / (float)Nr;
    float mu = sum[c] * inv;
    float var = sq[c] * inv - mu * mu;
    float rs = rsqrtf(var + BN_EPS);
    float sc = gamma[c] * rs;
    scale[c] = sc;
    shift[c] = beta[c] - mu * sc;
  }
}

// ---------------------------------------------------------------------------
// apply_bn: a = bf16(relu(scale*h + shift))
// ---------------------------------------------------------------------------
__global__ __launch_bounds__(256) void apply_bn(const u16* __restrict__ h,
                                                const float* __restrict__ scale,
                                                const float* __restrict__ shift,
                                                u16* __restrict__ a, int Nr) {
  int g = blockIdx.x * 256 + threadIdx.x;
  int coff = (g & 15) * 8;
  float sc[8], sh[8];
  #pragma unroll
  for (int j = 0; j < 8; ++j) { sc[j] = scale[coff + j]; sh[j] = shift[coff + j]; }
  int total = Nr * 16, stride = gridDim.x * 256;
  for (int idx = g; idx < total; idx += stride) {
    u16x8 v = *(const u16x8*)(h + (size_t)idx * 8);
    u16x8 o;
    #pragma unroll
    for (int j = 0; j < 8; ++j) {
      float f = fmaxf(sc[j] * bf2f(v[j]) + sh[j], 0.f);
      o[j] = f2bf(f);
    }
    *(u16x8*)(a + (size_t)idx * 8) = o;
  }
}

// ---------------------------------------------------------------------------
// final_k: out = relu(scale2*h2 + shift2 + x)   (f32 out)
// ---------------------------------------------------------------------------
__global__ __launch_bounds__(256) void final_k(const u16* __restrict__ h,
                                               const float* __restrict__ x,
                                               const float* __restrict__ scale,
                                               const float* __restrict__ shift,
                                               float* __restrict__ out, int Nr) {
  int g = blockIdx.x * 256 + threadIdx.x;
  int coff = (g & 15) * 8;
  float sc[8], sh[8];
  #pragma unroll
  for (int j = 0; j < 8; ++j) { sc[j] = scale[coff + j]; sh[j] = shift[coff + j]; }
  int total = Nr * 16, stride = gridDim.x * 256;
  for (int idx = g; idx < total; idx += stride) {
    u16x8 v = *(const u16x8*)(h + (size_t)idx * 8);
    const float* xs = x + (size_t)idx * 8;
    f32x4 xa = *(const f32x4*)xs;
    f32x4 xb = *(const f32x4*)(xs + 4);
    f32x4 oa, ob;
    #pragma unroll
    for (int j = 0; j < 4; ++j) {
      oa[j] = fmaxf(sc[j] * bf2f(v[j]) + sh[j] + xa[j], 0.f);
      ob[j] = fmaxf(sc[4 + j] * bf2f(v[4 + j]) + sh[4 + j] + xb[j], 0.f);
    }
    float* os = out + (size_t)idx * 8;
    *(f32x4*)os = oa;
    *(f32x4*)(os + 4) = ob;
  }
}

// ---------------------------------------------------------------------------
extern "C" void kernel_launch(void* const* d_in, const int* in_sizes, int n_in,
                              void* d_out, int out_size, void* d_ws, size_t ws_size,
                              hipStream_t stream) {
  const float* x  = (const float*)d_in[0];
  const float* W1 = (const float*)d_in[1];
  const float* W2 = (const float*)d_in[2];
  const float* g1 = (const float*)d_in[3];
  const float* b1 = (const float*)d_in[4];
  const float* g2 = (const float*)d_in[5];
  const float* b2 = (const float*)d_in[6];
  const int* nbr  = (const int*)d_in[7];
  float* out = (float*)d_out;
  const int Nr = in_sizes[0] / CH;   // 500000

  char* ws = (char*)d_ws;
  size_t offA = 0;
  size_t szA = (size_t)(Nr + 1) * CH * 2;           // bf16 x / a1 (+ zero row)
  size_t offB = (offA + szA + 255) & ~(size_t)255;  // bf16 h1 / h2
  size_t szB = (size_t)Nr * CH * 2;
  size_t offW1 = (offB + szB + 255) & ~(size_t)255;
  size_t offW2 = offW1 + (size_t)9 * CH * CH * 2;
  size_t offS  = offW2 + (size_t)9 * CH * CH * 2;

  u16* bufA = (u16*)(ws + offA);
  u16* bufB = (u16*)(ws + offB);
  u16* Wt1  = (u16*)(ws + offW1);
  u16* Wt2  = (u16*)(ws + offW2);
  float* stats = (float*)(ws + offS);
  float *sum1 = stats,       *sq1 = stats + 128;
  float *sum2 = stats + 256, *sq2 = stats + 384;
  float *sc1 = stats + 512, *sh1 = stats + 640;
  float *sc2 = stats + 768, *sh2 = stats + 896;

  hipMemsetAsync(stats, 0, 512 * sizeof(float), stream);
  prep_x<<<2048, 256, 0, stream>>>(x, bufA, Nr);
  prep_w<<<18, 256, 0, stream>>>(W1, W2, Wt1, Wt2);

  int nblk = (Nr + TM - 1) / TM;
  conv_k<<<nblk, 256, 0, stream>>>(bufA, Wt1, nbr, bufB, sum1, sq1, Nr);
  finalize_stats<<<1, 128, 0, stream>>>(sum1, sq1, g1, b1, sc1, sh1, Nr);
  apply_bn<<<2048, 256, 0, stream>>>(bufB, sc1, sh1, bufA, Nr);
  conv_k<<<nblk, 256, 0, stream>>>(bufA, Wt2, nbr, bufB, sum2, sq2, Nr);
  finalize_stats<<<1, 128, 0, stream>>>(sum2, sq2, g2, b2, sc2, sh2, Nr);
  final_k<<<2048, 256, 0, stream>>>(bufB, x, sc2, sh2, out, Nr);
}